// Round 13
// baseline (67.016 us; speedup 1.0000x reference)
//
#include <hip/hip_runtime.h>
#include <hip/hip_fp16.h>
#include <math.h>

namespace {

constexpr int DD = 1024;        // d
constexpr int NC = 3072;        // columns of x
constexpr int NG = 768;         // float4 groups per x row
constexpr int DG = 256;         // float4 groups per out row
constexpr int NROWS = 8192;     // B*T
constexpr int CH1 = 128;        // col-stat chunks (K1 grid.y)
constexpr float GAMMA = 5.0f;
constexpr float EPS_NORM = 1e-5f;
constexpr float EPS_W = 1e-8f;
constexpr float ZCLAMP = 15.0f; // sigma(15)=1-3e-7

typedef float nfloat4 __attribute__((ext_vector_type(4)));

struct Params {
  const float *x;
  const float *wq, *aq, *gq, *betaq;
  const float *wk, *ak, *gk, *betak;
  const float *wv, *av, *gv, *betav;
  const float *g_out, *b_out;
  float *out;
  float *psum, *psq;      // [CH1][NC] per-chunk partials (no zeroing needed)
  float *osum, *osq;      // [DD] atomic accumulators (zeroed by K2)
  float *A_arr, *B_arr;   // [3][NC]; gamma folded into q, col-mean folded into B
  unsigned short *o_arr;  // [NROWS][DD] fp16
};

__device__ __forceinline__ void acc4(float4& s, float4& q, float4 v) {
  s.x += v.x; s.y += v.y; s.z += v.z; s.w += v.w;
  q.x += v.x * v.x; q.y += v.y * v.y; q.z += v.z * v.z; q.w += v.w * v.w;
}

// Householder QR (LAPACK sign convention) of 3x3 a[d]; write folded coefs:
// norm_h_j = xi * A[j] + B[j]  (gamma folded into q-branch, mean into B).
__device__ __forceinline__ void qr_coef(const Params& P, int c, float mean, float var) {
  int p = c >> 10;            // 0=q,1=k,2=v
  int d = c & (DD - 1);
  const float* w    = (p == 0) ? P.wq    : (p == 1) ? P.wk    : P.wv;
  const float* a    = (p == 0) ? P.aq    : (p == 1) ? P.ak    : P.av;
  const float* g    = (p == 0) ? P.gq    : (p == 1) ? P.gk    : P.gv;
  const float* beta = (p == 0) ? P.betaq : (p == 1) ? P.betak : P.betav;
  float gam = (p == 0) ? GAMMA : 1.0f;

  float A[3][3];
  #pragma unroll
  for (int i = 0; i < 3; ++i)
    #pragma unroll
    for (int j = 0; j < 3; ++j) A[i][j] = a[(d * 3 + i) * 3 + j];

  float v1y = 0.f, v1z = 0.f, v2z = 0.f, t1 = 0.f, t2 = 0.f;
  {
    float alpha = A[0][0];
    float xn2 = A[1][0] * A[1][0] + A[2][0] * A[2][0];
    if (xn2 > 0.f) {
      float beta_ = -copysignf(sqrtf(alpha * alpha + xn2), alpha);
      t1 = (beta_ - alpha) / beta_;
      float inv = 1.0f / (alpha - beta_);
      v1y = A[1][0] * inv; v1z = A[2][0] * inv;
      #pragma unroll
      for (int j = 1; j < 3; ++j) {
        float dot = A[0][j] + A[1][j] * v1y + A[2][j] * v1z;
        float f = t1 * dot;
        A[0][j] -= f; A[1][j] -= f * v1y; A[2][j] -= f * v1z;
      }
    }
  }
  {
    float alpha = A[1][1], x2 = A[2][1];
    if (x2 != 0.f) {
      float beta_ = -copysignf(sqrtf(alpha * alpha + x2 * x2), alpha);
      t2 = (beta_ - alpha) / beta_;
      v2z = x2 / (alpha - beta_);
    }
  }
  float v1[3] = {1.f, v1y, v1z};
  float v2[3] = {0.f, 1.f, v2z};
  float v12 = v1y + v1z * v2z;
  float sp0 = log1pf(expf(w[d * 3 + 0]));
  float sp1 = log1pf(expf(w[d * 3 + 1]));
  float sp2 = log1pf(expf(w[d * 3 + 2]));
  #pragma unroll
  for (int j = 0; j < 3; ++j) {
    float Q0 = ((0 == j) ? 1.f : 0.f) - t1 * v1[0] * v1[j] - t2 * v2[0] * v2[j]
               + t1 * t2 * v12 * v1[0] * v2[j];
    float Q1 = ((1 == j) ? 1.f : 0.f) - t1 * v1[1] * v1[j] - t2 * v2[1] * v2[j]
               + t1 * t2 * v12 * v1[1] * v2[j];
    float Q2 = ((2 == j) ? 1.f : 0.f) - t1 * v1[2] * v1[j] - t2 * v2[2] * v2[j]
               + t1 * t2 * v12 * v1[2] * v2[j];
    float W = sp0 * Q0 + sp1 * Q1 + sp2 * Q2;
    float s = W * g[d * 3 + j] / sqrtf(W * W * var + EPS_NORM);
    P.A_arr[j * NC + c] = gam * s;
    P.B_arr[j * NC + c] = gam * (beta[d * 3 + j] - mean * s);
  }
}

struct CoefReg {
  float4 Aq[3], Bq[3], Ak[3], Bk[3], Av[3], Bv[3];
};

__device__ __forceinline__ CoefReg load_coefs(const Params& P, int tg) {
  CoefReg C;
  #pragma unroll
  for (int j = 0; j < 3; ++j) {
    C.Aq[j] = ((const float4*)(P.A_arr + j * NC))[tg];
    C.Ak[j] = ((const float4*)(P.A_arr + j * NC + DD))[tg];
    C.Av[j] = ((const float4*)(P.A_arr + j * NC + 2 * DD))[tg];
    C.Bq[j] = ((const float4*)(P.B_arr + j * NC))[tg];
    C.Bk[j] = ((const float4*)(P.B_arr + j * NC + DD))[tg];
    C.Bv[j] = ((const float4*)(P.B_arr + j * NC + 2 * DD))[tg];
  }
  return C;
}

__device__ __forceinline__ float4 contract4(float4 xq, float4 xk, float4 xv,
                                            const CoefReg& C) {
  float4 ov;
  #pragma unroll
  for (int kk = 0; kk < 4; ++kk) {
    float xqv = ((const float*)&xq)[kk];
    float xkv = ((const float*)&xk)[kk];
    float xvv = ((const float*)&xv)[kk];
    float Q[3], K[3], V[3];
    #pragma unroll
    for (int j = 0; j < 3; ++j) {
      Q[j] = fmaf(xqv, ((const float*)&C.Aq[j])[kk], ((const float*)&C.Bq[j])[kk]);
      K[j] = fmaf(xkv, ((const float*)&C.Ak[j])[kk], ((const float*)&C.Bk[j])[kk]);
      V[j] = fmaf(xvv, ((const float*)&C.Av[j])[kk], ((const float*)&C.Bv[j])[kk]);
    }
    // product form: multiply num & den by (1+e0)(1+e1)(1+e2); 3 exp + 1 div
    float e0 = __expf(fminf(Q[0] * K[0], ZCLAMP));
    float e1 = __expf(fminf(Q[1] * K[1], ZCLAMP));
    float e2 = __expf(fminf(Q[2] * K[2], ZCLAMP));
    float a0 = 1.f + e0, a1 = 1.f + e1, a2 = 1.f + e2;
    float a01 = a0 * a1, a12 = a1 * a2, a02 = a0 * a2;
    float w0 = e0 * a12, w1 = e1 * a02, w2 = e2 * a01;
    float num = w0 * V[0] + w1 * V[1] + w2 * V[2];
    float den = w0 + w1 + w2 + EPS_W * (a01 * a2);
    ((float*)&ov)[kk] = num / den;
  }
  return ov;
}

// ============ K1: col stats -> per-chunk partials. grid (12,CH1) ============
// block: 64 float4-col-groups x 64 rows; LDS-reduce, plain coalesced store.
__global__ __launch_bounds__(256, 4) void k1_col_stats(Params P) {
  __shared__ float4 lds_s[4][64];
  __shared__ float4 lds_q[4][64];
  const int t = threadIdx.x;
  const int lane = t & 63;
  const int slice = t >> 6;               // 0..3
  const int cg = blockIdx.x * 64 + lane;  // float4 col group 0..767
  const int r0 = blockIdx.y * 64 + slice * 16;
  const float4* x4 = (const float4*)P.x;
  float4 s = {0,0,0,0}, q = {0,0,0,0};
  #pragma unroll
  for (int r = 0; r < 16; ++r) {
    acc4(s, q, x4[(size_t)(r0 + r) * NG + cg]);
  }
  lds_s[slice][lane] = s;
  lds_q[slice][lane] = q;
  __syncthreads();
  // thread t owns scalar column c = blockIdx.x*256 + t
  float ssum = 0.f, ssq = 0.f;
  #pragma unroll
  for (int i = 0; i < 4; ++i) {
    ssum += ((const float*)&lds_s[i][t >> 2])[t & 3];
    ssq  += ((const float*)&lds_q[i][t >> 2])[t & 3];
  }
  P.psum[(size_t)blockIdx.y * NC + blockIdx.x * 256 + t] = ssum;
  P.psq [(size_t)blockIdx.y * NC + blockIdx.x * 256 + t] = ssq;
}

// ====== K2: reduce partials + QR + zero osum/osq. grid 12, block 256 ======
__global__ __launch_bounds__(256, 4) void k2_coef(Params P) {
  const int t = threadIdx.x;
  const int c = blockIdx.x * 256 + t;  // 0..3071
  float s = 0.f, q = 0.f;
  #pragma unroll 4
  for (int ch = 0; ch < CH1; ++ch) {
    s += P.psum[(size_t)ch * NC + c];
    q += P.psq [(size_t)ch * NC + c];
  }
  // absorb the memset: zero the K3 atomic accumulators
  if (blockIdx.x == 0) ((float4*)P.osum)[t] = float4{0.f, 0.f, 0.f, 0.f};
  if (blockIdx.x == 1) ((float4*)P.osq )[t] = float4{0.f, 0.f, 0.f, 0.f};
  float mean = s / NROWS;
  float var = q / NROWS - mean * mean;
  if (var < 0.f) var = 0.f;
  qr_coef(P, c, mean, var);
}

// ============ K3: contraction + store o fp16 + atomic out-stats ============
// grid (4, 256), block 256 (4 waves). launch_bounds(256,2): VGPR cap 256 --
// r12 A/B proved (256,4) squeezes this kernel into scratch spills.
__global__ __launch_bounds__(256, 2) void k3_main(Params P) {
  __shared__ float4 lds_s[4][64];
  __shared__ float4 lds_q[4][64];
  const int t = threadIdx.x;
  const int lane = t & 63;
  const int slice = t >> 6;
  const int tg = blockIdx.x * 64 + lane;  // float4 d-group 0..255
  const int r0 = blockIdx.y * 32 + slice * 8;
  const float4* x4 = (const float4*)P.x;
  ushort4* o4 = (ushort4*)P.o_arr;
  CoefReg C = load_coefs(P, tg);
  float4 s = {0,0,0,0}, q = {0,0,0,0};
  #pragma unroll
  for (int r = 0; r < 8; ++r) {
    size_t base = (size_t)(r0 + r) * NG;
    float4 xq = x4[base + tg];
    float4 xk = x4[base + 256 + tg];
    float4 xv = x4[base + 512 + tg];
    float4 ov = contract4(xq, xk, xv, C);
    ushort4 oh;
    oh.x = __half_as_ushort(__float2half(ov.x));
    oh.y = __half_as_ushort(__float2half(ov.y));
    oh.z = __half_as_ushort(__float2half(ov.z));
    oh.w = __half_as_ushort(__float2half(ov.w));
    o4[(size_t)(r0 + r) * DG + tg] = oh;
    acc4(s, q, ov);
  }
  lds_s[slice][lane] = s;
  lds_q[slice][lane] = q;
  __syncthreads();
  float ssum = 0.f, ssq = 0.f;
  #pragma unroll
  for (int i = 0; i < 4; ++i) {
    ssum += ((const float*)&lds_s[i][t >> 2])[t & 3];
    ssq  += ((const float*)&lds_q[i][t >> 2])[t & 3];
  }
  atomicAdd(&P.osum[blockIdx.x * 256 + t], ssum);
  atomicAdd(&P.osq[blockIdx.x * 256 + t], ssq);
}

// ============ K4: per-thread stats recompute + normalize + write ============
// grid 2048, block 256 (4 rows/block). m/sc derived from the 8 KB
// accumulators (L2-broadcast) -- no separate stats kernel.
__global__ __launch_bounds__(256, 8) void k4_final(Params P) {
  const int t = threadIdx.x;
  float4 s4 = ((const float4*)P.osum)[t];
  float4 q4 = ((const float4*)P.osq)[t];
  float4 g4 = ((const float4*)P.g_out)[t];
  float4 b4 = ((const float4*)P.b_out)[t];
  float4 m, sc;
  #pragma unroll
  for (int kk = 0; kk < 4; ++kk) {
    float mean = ((const float*)&s4)[kk] / NROWS;
    float var = ((const float*)&q4)[kk] / NROWS - mean * mean;
    if (var < 0.f) var = 0.f;
    ((float*)&m)[kk] = mean;
    ((float*)&sc)[kk] = ((const float*)&g4)[kk] / sqrtf(var + EPS_NORM);
  }
  const int r0 = blockIdx.x * 4;
  const ushort4* o4 = (const ushort4*)P.o_arr;
  float4* out4 = (float4*)P.out;
  #pragma unroll
  for (int rr = 0; rr < 4; ++rr) {
    size_t idx = (size_t)(r0 + rr) * DG + t;
    ushort4 oh = o4[idx];
    nfloat4 y;
    y.x = (__half2float(__ushort_as_half(oh.x)) - m.x) * sc.x + b4.x;
    y.y = (__half2float(__ushort_as_half(oh.y)) - m.y) * sc.y + b4.y;
    y.z = (__half2float(__ushort_as_half(oh.z)) - m.z) * sc.z + b4.z;
    y.w = (__half2float(__ushort_as_half(oh.w)) - m.w) * sc.w + b4.w;
    __builtin_nontemporal_store(y, (nfloat4*)&out4[idx]);
  }
}

}  // namespace

extern "C" void kernel_launch(void* const* d_in, const int* in_sizes, int n_in,
                              void* d_out, int out_size, void* d_ws, size_t ws_size,
                              hipStream_t stream) {
  Params P;
  P.x     = (const float*)d_in[0];
  P.wq    = (const float*)d_in[1];
  P.aq    = (const float*)d_in[3];
  P.gq    = (const float*)d_in[4];
  P.betaq = (const float*)d_in[5];
  P.wk    = (const float*)d_in[6];
  P.ak    = (const float*)d_in[8];
  P.gk    = (const float*)d_in[9];
  P.betak = (const float*)d_in[10];
  P.wv    = (const float*)d_in[11];
  P.av    = (const float*)d_in[13];
  P.gv    = (const float*)d_in[14];
  P.betav = (const float*)d_in[15];
  P.g_out = (const float*)d_in[16];
  P.b_out = (const float*)d_in[17];
  P.out   = (float*)d_out;

  float* ws = (float*)d_ws;
  P.psum  = ws;  ws += (size_t)CH1 * NC;   // 1.57 MB
  P.psq   = ws;  ws += (size_t)CH1 * NC;   // 1.57 MB
  P.osum  = ws;  ws += DD;
  P.osq   = ws;  ws += DD;
  P.A_arr = ws;  ws += 3 * NC;
  P.B_arr = ws;  ws += 3 * NC;
  P.o_arr = (unsigned short*)ws;           // 16 MB fp16 [NROWS][DD]

  k1_col_stats<<<dim3(12, CH1), dim3(256), 0, stream>>>(P);
  k2_coef<<<dim3(12), dim3(256), 0, stream>>>(P);
  k3_main<<<dim3(4, 256), dim3(256), 0, stream>>>(P);
  k4_final<<<dim3(2048), dim3(256), 0, stream>>>(P);
}

// Round 14
// 58.202 us; speedup vs baseline: 1.1514x; 1.1514x over previous
//
#include <hip/hip_runtime.h>
#include <hip/hip_fp16.h>
#include <math.h>

namespace {

constexpr int DD = 1024;        // d
constexpr int NC = 3072;        // columns of x
constexpr int NG = 768;         // float4 groups per x row
constexpr int DG = 256;         // float4 groups per out row
constexpr int NROWS = 8192;     // B*T
constexpr int CH1 = 128;        // col-stat chunks (K1 grid.y)
constexpr float GAMMA = 5.0f;
constexpr float EPS_NORM = 1e-5f;
constexpr float EPS_W = 1e-8f;
constexpr float ZCLAMP = 15.0f; // sigma(15)=1-3e-7

typedef float nfloat4 __attribute__((ext_vector_type(4)));

struct Params {
  const float *x;
  const float *wq, *aq, *gq, *betaq;
  const float *wk, *ak, *gk, *betak;
  const float *wv, *av, *gv, *betav;
  const float *g_out, *b_out;
  float *out;
  float *psum, *psq;      // [CH1][NC] per-chunk partials (no zeroing needed)
  float *osum, *osq;      // [DD] atomic accumulators (zeroed by K2 blocks 0/1)
  float *A_arr, *B_arr;   // [3][NC]; gamma folded into q, col-mean folded into B
  unsigned short *o_arr;  // [NROWS][DD] fp16
};

__device__ __forceinline__ void acc4(float4& s, float4& q, float4 v) {
  s.x += v.x; s.y += v.y; s.z += v.z; s.w += v.w;
  q.x += v.x * v.x; q.y += v.y * v.y; q.z += v.z * v.z; q.w += v.w * v.w;
}

// Householder QR (LAPACK sign convention) of 3x3 a[d]; write folded coefs:
// norm_h_j = xi * A[j] + B[j]  (gamma folded into q-branch, mean into B).
__device__ __forceinline__ void qr_coef(const Params& P, int c, float mean, float var) {
  int p = c >> 10;            // 0=q,1=k,2=v
  int d = c & (DD - 1);
  const float* w    = (p == 0) ? P.wq    : (p == 1) ? P.wk    : P.wv;
  const float* a    = (p == 0) ? P.aq    : (p == 1) ? P.ak    : P.av;
  const float* g    = (p == 0) ? P.gq    : (p == 1) ? P.gk    : P.gv;
  const float* beta = (p == 0) ? P.betaq : (p == 1) ? P.betak : P.betav;
  float gam = (p == 0) ? GAMMA : 1.0f;

  float A[3][3];
  #pragma unroll
  for (int i = 0; i < 3; ++i)
    #pragma unroll
    for (int j = 0; j < 3; ++j) A[i][j] = a[(d * 3 + i) * 3 + j];

  float v1y = 0.f, v1z = 0.f, v2z = 0.f, t1 = 0.f, t2 = 0.f;
  {
    float alpha = A[0][0];
    float xn2 = A[1][0] * A[1][0] + A[2][0] * A[2][0];
    if (xn2 > 0.f) {
      float beta_ = -copysignf(sqrtf(alpha * alpha + xn2), alpha);
      t1 = (beta_ - alpha) / beta_;
      float inv = 1.0f / (alpha - beta_);
      v1y = A[1][0] * inv; v1z = A[2][0] * inv;
      #pragma unroll
      for (int j = 1; j < 3; ++j) {
        float dot = A[0][j] + A[1][j] * v1y + A[2][j] * v1z;
        float f = t1 * dot;
        A[0][j] -= f; A[1][j] -= f * v1y; A[2][j] -= f * v1z;
      }
    }
  }
  {
    float alpha = A[1][1], x2 = A[2][1];
    if (x2 != 0.f) {
      float beta_ = -copysignf(sqrtf(alpha * alpha + x2 * x2), alpha);
      t2 = (beta_ - alpha) / beta_;
      v2z = x2 / (alpha - beta_);
    }
  }
  float v1[3] = {1.f, v1y, v1z};
  float v2[3] = {0.f, 1.f, v2z};
  float v12 = v1y + v1z * v2z;
  float sp0 = log1pf(expf(w[d * 3 + 0]));
  float sp1 = log1pf(expf(w[d * 3 + 1]));
  float sp2 = log1pf(expf(w[d * 3 + 2]));
  #pragma unroll
  for (int j = 0; j < 3; ++j) {
    float Q0 = ((0 == j) ? 1.f : 0.f) - t1 * v1[0] * v1[j] - t2 * v2[0] * v2[j]
               + t1 * t2 * v12 * v1[0] * v2[j];
    float Q1 = ((1 == j) ? 1.f : 0.f) - t1 * v1[1] * v1[j] - t2 * v2[1] * v2[j]
               + t1 * t2 * v12 * v1[1] * v2[j];
    float Q2 = ((2 == j) ? 1.f : 0.f) - t1 * v1[2] * v1[j] - t2 * v2[2] * v2[j]
               + t1 * t2 * v12 * v1[2] * v2[j];
    float W = sp0 * Q0 + sp1 * Q1 + sp2 * Q2;
    float s = W * g[d * 3 + j] / sqrtf(W * W * var + EPS_NORM);
    P.A_arr[j * NC + c] = gam * s;
    P.B_arr[j * NC + c] = gam * (beta[d * 3 + j] - mean * s);
  }
}

struct CoefReg {
  float4 Aq[3], Bq[3], Ak[3], Bk[3], Av[3], Bv[3];
};

__device__ __forceinline__ CoefReg load_coefs(const Params& P, int tg) {
  CoefReg C;
  #pragma unroll
  for (int j = 0; j < 3; ++j) {
    C.Aq[j] = ((const float4*)(P.A_arr + j * NC))[tg];
    C.Ak[j] = ((const float4*)(P.A_arr + j * NC + DD))[tg];
    C.Av[j] = ((const float4*)(P.A_arr + j * NC + 2 * DD))[tg];
    C.Bq[j] = ((const float4*)(P.B_arr + j * NC))[tg];
    C.Bk[j] = ((const float4*)(P.B_arr + j * NC + DD))[tg];
    C.Bv[j] = ((const float4*)(P.B_arr + j * NC + 2 * DD))[tg];
  }
  return C;
}

__device__ __forceinline__ float4 contract4(float4 xq, float4 xk, float4 xv,
                                            const CoefReg& C) {
  float4 ov;
  #pragma unroll
  for (int kk = 0; kk < 4; ++kk) {
    float xqv = ((const float*)&xq)[kk];
    float xkv = ((const float*)&xk)[kk];
    float xvv = ((const float*)&xv)[kk];
    float Q[3], K[3], V[3];
    #pragma unroll
    for (int j = 0; j < 3; ++j) {
      Q[j] = fmaf(xqv, ((const float*)&C.Aq[j])[kk], ((const float*)&C.Bq[j])[kk]);
      K[j] = fmaf(xkv, ((const float*)&C.Ak[j])[kk], ((const float*)&C.Bk[j])[kk]);
      V[j] = fmaf(xvv, ((const float*)&C.Av[j])[kk], ((const float*)&C.Bv[j])[kk]);
    }
    // product form: multiply num & den by (1+e0)(1+e1)(1+e2); 3 exp + 1 div
    float e0 = __expf(fminf(Q[0] * K[0], ZCLAMP));
    float e1 = __expf(fminf(Q[1] * K[1], ZCLAMP));
    float e2 = __expf(fminf(Q[2] * K[2], ZCLAMP));
    float a0 = 1.f + e0, a1 = 1.f + e1, a2 = 1.f + e2;
    float a01 = a0 * a1, a12 = a1 * a2, a02 = a0 * a2;
    float w0 = e0 * a12, w1 = e1 * a02, w2 = e2 * a01;
    float num = w0 * V[0] + w1 * V[1] + w2 * V[2];
    float den = w0 + w1 + w2 + EPS_W * (a01 * a2);
    ((float*)&ov)[kk] = num / den;
  }
  return ov;
}

// ============ K1: col stats -> per-chunk partials. grid (12,CH1) ============
// block: 64 float4-col-groups x 64 rows; LDS-reduce, plain coalesced store.
__global__ __launch_bounds__(256, 4) void k1_col_stats(Params P) {
  __shared__ float4 lds_s[4][64];
  __shared__ float4 lds_q[4][64];
  const int t = threadIdx.x;
  const int lane = t & 63;
  const int slice = t >> 6;               // 0..3
  const int cg = blockIdx.x * 64 + lane;  // float4 col group 0..767
  const int r0 = blockIdx.y * 64 + slice * 16;
  const float4* x4 = (const float4*)P.x;
  float4 s = {0,0,0,0}, q = {0,0,0,0};
  #pragma unroll 8
  for (int r = 0; r < 16; ++r) {
    acc4(s, q, x4[(size_t)(r0 + r) * NG + cg]);
  }
  lds_s[slice][lane] = s;
  lds_q[slice][lane] = q;
  __syncthreads();
  // thread t owns scalar column c = blockIdx.x*256 + t
  float ssum = 0.f, ssq = 0.f;
  #pragma unroll
  for (int i = 0; i < 4; ++i) {
    ssum += ((const float*)&lds_s[i][t >> 2])[t & 3];
    ssq  += ((const float*)&lds_q[i][t >> 2])[t & 3];
  }
  P.psum[(size_t)blockIdx.y * NC + blockIdx.x * 256 + t] = ssum;
  P.psq [(size_t)blockIdx.y * NC + blockIdx.x * 256 + t] = ssq;
}

// ====== K2: parallel partial-reduce + QR + zero osum/osq. grid 48 ======
// block: 64 cols (lane-coalesced), 4 slices x 32 chunks; LDS reduce;
// 64 QRs per block. Blocks 0/1 zero the K3 atomic accumulators.
__global__ __launch_bounds__(256, 4) void k2_coef(Params P) {
  __shared__ float lds_s[4][64];
  __shared__ float lds_q[4][64];
  const int t = threadIdx.x;
  const int lane = t & 63;
  const int slice = t >> 6;               // 0..3
  const int c = blockIdx.x * 64 + lane;   // 0..3071
  float s = 0.f, q = 0.f;
  #pragma unroll 8
  for (int i = 0; i < 32; ++i) {
    int ch = slice * 32 + i;              // 0..127
    s += P.psum[(size_t)ch * NC + c];
    q += P.psq [(size_t)ch * NC + c];
  }
  lds_s[slice][lane] = s;
  lds_q[slice][lane] = q;
  // absorb the memset: zero the K3 atomic accumulators (1024 floats each)
  if (blockIdx.x == 0) ((float4*)P.osum)[t] = float4{0.f, 0.f, 0.f, 0.f};
  if (blockIdx.x == 1) ((float4*)P.osq )[t] = float4{0.f, 0.f, 0.f, 0.f};
  __syncthreads();
  if (t < 64) {
    float ss = lds_s[0][t] + lds_s[1][t] + lds_s[2][t] + lds_s[3][t];
    float qq = lds_q[0][t] + lds_q[1][t] + lds_q[2][t] + lds_q[3][t];
    float mean = ss / NROWS;
    float var = qq / NROWS - mean * mean;
    if (var < 0.f) var = 0.f;
    qr_coef(P, blockIdx.x * 64 + t, mean, var);
  }
}

// ============ K3: contraction + store o fp16 + atomic out-stats ============
// grid (4, 256), block 256 (4 waves). launch_bounds(256,2): VGPR cap 256 --
// r12 A/B proved (256,4) squeezes this kernel into scratch spills.
__global__ __launch_bounds__(256, 2) void k3_main(Params P) {
  __shared__ float4 lds_s[4][64];
  __shared__ float4 lds_q[4][64];
  const int t = threadIdx.x;
  const int lane = t & 63;
  const int slice = t >> 6;
  const int tg = blockIdx.x * 64 + lane;  // float4 d-group 0..255
  const int r0 = blockIdx.y * 32 + slice * 8;
  const float4* x4 = (const float4*)P.x;
  ushort4* o4 = (ushort4*)P.o_arr;
  CoefReg C = load_coefs(P, tg);
  float4 s = {0,0,0,0}, q = {0,0,0,0};
  #pragma unroll
  for (int r = 0; r < 8; ++r) {
    size_t base = (size_t)(r0 + r) * NG;
    float4 xq = x4[base + tg];
    float4 xk = x4[base + 256 + tg];
    float4 xv = x4[base + 512 + tg];
    float4 ov = contract4(xq, xk, xv, C);
    ushort4 oh;
    oh.x = __half_as_ushort(__float2half(ov.x));
    oh.y = __half_as_ushort(__float2half(ov.y));
    oh.z = __half_as_ushort(__float2half(ov.z));
    oh.w = __half_as_ushort(__float2half(ov.w));
    o4[(size_t)(r0 + r) * DG + tg] = oh;
    acc4(s, q, ov);
  }
  lds_s[slice][lane] = s;
  lds_q[slice][lane] = q;
  __syncthreads();
  float ssum = 0.f, ssq = 0.f;
  #pragma unroll
  for (int i = 0; i < 4; ++i) {
    ssum += ((const float*)&lds_s[i][t >> 2])[t & 3];
    ssq  += ((const float*)&lds_q[i][t >> 2])[t & 3];
  }
  atomicAdd(&P.osum[blockIdx.x * 256 + t], ssum);
  atomicAdd(&P.osq[blockIdx.x * 256 + t], ssq);
}

// ============ K4: per-thread stats recompute + normalize + write ============
// grid 2048, block 256 (4 rows/block). m/sc derived from the 8 KB
// accumulators (L2-broadcast) -- no separate stats kernel.
__global__ __launch_bounds__(256, 8) void k4_final(Params P) {
  const int t = threadIdx.x;
  float4 s4 = ((const float4*)P.osum)[t];
  float4 q4 = ((const float4*)P.osq)[t];
  float4 g4 = ((const float4*)P.g_out)[t];
  float4 b4 = ((const float4*)P.b_out)[t];
  float4 m, sc;
  #pragma unroll
  for (int kk = 0; kk < 4; ++kk) {
    float mean = ((const float*)&s4)[kk] / NROWS;
    float var = ((const float*)&q4)[kk] / NROWS - mean * mean;
    if (var < 0.f) var = 0.f;
    ((float*)&m)[kk] = mean;
    ((float*)&sc)[kk] = ((const float*)&g4)[kk] / sqrtf(var + EPS_NORM);
  }
  const int r0 = blockIdx.x * 4;
  const ushort4* o4 = (const ushort4*)P.o_arr;
  float4* out4 = (float4*)P.out;
  #pragma unroll
  for (int rr = 0; rr < 4; ++rr) {
    size_t idx = (size_t)(r0 + rr) * DG + t;
    ushort4 oh = o4[idx];
    nfloat4 y;
    y.x = (__half2float(__ushort_as_half(oh.x)) - m.x) * sc.x + b4.x;
    y.y = (__half2float(__ushort_as_half(oh.y)) - m.y) * sc.y + b4.y;
    y.z = (__half2float(__ushort_as_half(oh.z)) - m.z) * sc.z + b4.z;
    y.w = (__half2float(__ushort_as_half(oh.w)) - m.w) * sc.w + b4.w;
    __builtin_nontemporal_store(y, (nfloat4*)&out4[idx]);
  }
}

}  // namespace

extern "C" void kernel_launch(void* const* d_in, const int* in_sizes, int n_in,
                              void* d_out, int out_size, void* d_ws, size_t ws_size,
                              hipStream_t stream) {
  Params P;
  P.x     = (const float*)d_in[0];
  P.wq    = (const float*)d_in[1];
  P.aq    = (const float*)d_in[3];
  P.gq    = (const float*)d_in[4];
  P.betaq = (const float*)d_in[5];
  P.wk    = (const float*)d_in[6];
  P.ak    = (const float*)d_in[8];
  P.gk    = (const float*)d_in[9];
  P.betak = (const float*)d_in[10];
  P.wv    = (const float*)d_in[11];
  P.av    = (const float*)d_in[13];
  P.gv    = (const float*)d_in[14];
  P.betav = (const float*)d_in[15];
  P.g_out = (const float*)d_in[16];
  P.b_out = (const float*)d_in[17];
  P.out   = (float*)d_out;

  float* ws = (float*)d_ws;
  P.psum  = ws;  ws += (size_t)CH1 * NC;   // 1.57 MB
  P.psq   = ws;  ws += (size_t)CH1 * NC;   // 1.57 MB
  P.osum  = ws;  ws += DD;
  P.osq   = ws;  ws += DD;
  P.A_arr = ws;  ws += 3 * NC;
  P.B_arr = ws;  ws += 3 * NC;
  P.o_arr = (unsigned short*)ws;           // 16 MB fp16 [NROWS][DD]

  k1_col_stats<<<dim3(12, CH1), dim3(256), 0, stream>>>(P);
  k2_coef<<<dim3(48), dim3(256), 0, stream>>>(P);
  k3_main<<<dim3(4, 256), dim3(256), 0, stream>>>(P);
  k4_final<<<dim3(2048), dim3(256), 0, stream>>>(P);
}

// Round 15
// 58.074 us; speedup vs baseline: 1.1540x; 1.0022x over previous
//
#include <hip/hip_runtime.h>
#include <hip/hip_fp16.h>
#include <math.h>

namespace {

constexpr int DD = 1024;        // d
constexpr int NC = 3072;        // columns of x
constexpr int NG = 768;         // float4 groups per x row
constexpr int DG = 256;         // float4 groups per out row
constexpr int NROWS = 8192;     // B*T
constexpr int CH1 = 128;        // col-stat chunks (K1 grid.y)
constexpr float GAMMA = 5.0f;
constexpr float EPS_NORM = 1e-5f;
constexpr float EPS_W = 1e-8f;
constexpr float ZCLAMP = 15.0f; // sigma(15)=1-3e-7

typedef float nfloat4 __attribute__((ext_vector_type(4)));

struct Params {
  const float *x;
  const float *wq, *aq, *gq, *betaq;
  const float *wk, *ak, *gk, *betak;
  const float *wv, *av, *gv, *betav;
  const float *g_out, *b_out;
  float *out;
  float *psum, *psq;      // [CH1][NC] per-chunk partials (no zeroing needed)
  float *osum, *osq;      // [DD] atomic accumulators (zeroed by K2 blocks 0/1)
  float *A_arr, *B_arr;   // [3][NC]; gamma folded into q, col-mean folded into B
  unsigned short *o_arr;  // [NROWS][DD] fp16
};

__device__ __forceinline__ void acc4(float4& s, float4& q, float4 v) {
  s.x += v.x; s.y += v.y; s.z += v.z; s.w += v.w;
  q.x += v.x * v.x; q.y += v.y * v.y; q.z += v.z * v.z; q.w += v.w * v.w;
}

// Householder QR (LAPACK sign convention) of 3x3 a[d]; write folded coefs:
// norm_h_j = xi * A[j] + B[j]  (gamma folded into q-branch, mean into B).
__device__ __forceinline__ void qr_coef(const Params& P, int c, float mean, float var) {
  int p = c >> 10;            // 0=q,1=k,2=v
  int d = c & (DD - 1);
  const float* w    = (p == 0) ? P.wq    : (p == 1) ? P.wk    : P.wv;
  const float* a    = (p == 0) ? P.aq    : (p == 1) ? P.ak    : P.av;
  const float* g    = (p == 0) ? P.gq    : (p == 1) ? P.gk    : P.gv;
  const float* beta = (p == 0) ? P.betaq : (p == 1) ? P.betak : P.betav;
  float gam = (p == 0) ? GAMMA : 1.0f;

  float A[3][3];
  #pragma unroll
  for (int i = 0; i < 3; ++i)
    #pragma unroll
    for (int j = 0; j < 3; ++j) A[i][j] = a[(d * 3 + i) * 3 + j];

  float v1y = 0.f, v1z = 0.f, v2z = 0.f, t1 = 0.f, t2 = 0.f;
  {
    float alpha = A[0][0];
    float xn2 = A[1][0] * A[1][0] + A[2][0] * A[2][0];
    if (xn2 > 0.f) {
      float beta_ = -copysignf(sqrtf(alpha * alpha + xn2), alpha);
      t1 = (beta_ - alpha) / beta_;
      float inv = 1.0f / (alpha - beta_);
      v1y = A[1][0] * inv; v1z = A[2][0] * inv;
      #pragma unroll
      for (int j = 1; j < 3; ++j) {
        float dot = A[0][j] + A[1][j] * v1y + A[2][j] * v1z;
        float f = t1 * dot;
        A[0][j] -= f; A[1][j] -= f * v1y; A[2][j] -= f * v1z;
      }
    }
  }
  {
    float alpha = A[1][1], x2 = A[2][1];
    if (x2 != 0.f) {
      float beta_ = -copysignf(sqrtf(alpha * alpha + x2 * x2), alpha);
      t2 = (beta_ - alpha) / beta_;
      v2z = x2 / (alpha - beta_);
    }
  }
  float v1[3] = {1.f, v1y, v1z};
  float v2[3] = {0.f, 1.f, v2z};
  float v12 = v1y + v1z * v2z;
  float sp0 = log1pf(expf(w[d * 3 + 0]));
  float sp1 = log1pf(expf(w[d * 3 + 1]));
  float sp2 = log1pf(expf(w[d * 3 + 2]));
  #pragma unroll
  for (int j = 0; j < 3; ++j) {
    float Q0 = ((0 == j) ? 1.f : 0.f) - t1 * v1[0] * v1[j] - t2 * v2[0] * v2[j]
               + t1 * t2 * v12 * v1[0] * v2[j];
    float Q1 = ((1 == j) ? 1.f : 0.f) - t1 * v1[1] * v1[j] - t2 * v2[1] * v2[j]
               + t1 * t2 * v12 * v1[1] * v2[j];
    float Q2 = ((2 == j) ? 1.f : 0.f) - t1 * v1[2] * v1[j] - t2 * v2[2] * v2[j]
               + t1 * t2 * v12 * v1[2] * v2[j];
    float W = sp0 * Q0 + sp1 * Q1 + sp2 * Q2;
    float s = W * g[d * 3 + j] / sqrtf(W * W * var + EPS_NORM);
    P.A_arr[j * NC + c] = gam * s;
    P.B_arr[j * NC + c] = gam * (beta[d * 3 + j] - mean * s);
  }
}

struct CoefReg {
  float4 Aq[3], Bq[3], Ak[3], Bk[3], Av[3], Bv[3];
};

__device__ __forceinline__ CoefReg load_coefs(const Params& P, int tg) {
  CoefReg C;
  #pragma unroll
  for (int j = 0; j < 3; ++j) {
    C.Aq[j] = ((const float4*)(P.A_arr + j * NC))[tg];
    C.Ak[j] = ((const float4*)(P.A_arr + j * NC + DD))[tg];
    C.Av[j] = ((const float4*)(P.A_arr + j * NC + 2 * DD))[tg];
    C.Bq[j] = ((const float4*)(P.B_arr + j * NC))[tg];
    C.Bk[j] = ((const float4*)(P.B_arr + j * NC + DD))[tg];
    C.Bv[j] = ((const float4*)(P.B_arr + j * NC + 2 * DD))[tg];
  }
  return C;
}

__device__ __forceinline__ float4 contract4(float4 xq, float4 xk, float4 xv,
                                            const CoefReg& C) {
  float4 ov;
  #pragma unroll
  for (int kk = 0; kk < 4; ++kk) {
    float xqv = ((const float*)&xq)[kk];
    float xkv = ((const float*)&xk)[kk];
    float xvv = ((const float*)&xv)[kk];
    float Q[3], K[3], V[3];
    #pragma unroll
    for (int j = 0; j < 3; ++j) {
      Q[j] = fmaf(xqv, ((const float*)&C.Aq[j])[kk], ((const float*)&C.Bq[j])[kk]);
      K[j] = fmaf(xkv, ((const float*)&C.Ak[j])[kk], ((const float*)&C.Bk[j])[kk]);
      V[j] = fmaf(xvv, ((const float*)&C.Av[j])[kk], ((const float*)&C.Bv[j])[kk]);
    }
    // product form: multiply num & den by (1+e0)(1+e1)(1+e2); 3 exp + 1 div
    float e0 = __expf(fminf(Q[0] * K[0], ZCLAMP));
    float e1 = __expf(fminf(Q[1] * K[1], ZCLAMP));
    float e2 = __expf(fminf(Q[2] * K[2], ZCLAMP));
    float a0 = 1.f + e0, a1 = 1.f + e1, a2 = 1.f + e2;
    float a01 = a0 * a1, a12 = a1 * a2, a02 = a0 * a2;
    float w0 = e0 * a12, w1 = e1 * a02, w2 = e2 * a01;
    float num = w0 * V[0] + w1 * V[1] + w2 * V[2];
    float den = w0 + w1 + w2 + EPS_W * (a01 * a2);
    ((float*)&ov)[kk] = num / den;
  }
  return ov;
}

// ============ K1: col stats -> per-chunk partials. grid (12,CH1) ============
// block: 64 float4-col-groups x 64 rows; LDS-reduce, plain coalesced store.
__global__ __launch_bounds__(256, 4) void k1_col_stats(Params P) {
  __shared__ float4 lds_s[4][64];
  __shared__ float4 lds_q[4][64];
  const int t = threadIdx.x;
  const int lane = t & 63;
  const int slice = t >> 6;               // 0..3
  const int cg = blockIdx.x * 64 + lane;  // float4 col group 0..767
  const int r0 = blockIdx.y * 64 + slice * 16;
  const float4* x4 = (const float4*)P.x;
  float4 s = {0,0,0,0}, q = {0,0,0,0};
  #pragma unroll 8
  for (int r = 0; r < 16; ++r) {
    acc4(s, q, x4[(size_t)(r0 + r) * NG + cg]);
  }
  lds_s[slice][lane] = s;
  lds_q[slice][lane] = q;
  __syncthreads();
  // thread t owns scalar column c = blockIdx.x*256 + t
  float ssum = 0.f, ssq = 0.f;
  #pragma unroll
  for (int i = 0; i < 4; ++i) {
    ssum += ((const float*)&lds_s[i][t >> 2])[t & 3];
    ssq  += ((const float*)&lds_q[i][t >> 2])[t & 3];
  }
  P.psum[(size_t)blockIdx.y * NC + blockIdx.x * 256 + t] = ssum;
  P.psq [(size_t)blockIdx.y * NC + blockIdx.x * 256 + t] = ssq;
}

// ====== K2: parallel partial-reduce + QR + zero osum/osq. grid 48 ======
// block: 64 cols (lane-coalesced), 4 slices x 32 chunks; LDS reduce;
// 64 QRs per block. Blocks 0/1 zero the K3 atomic accumulators.
__global__ __launch_bounds__(256, 4) void k2_coef(Params P) {
  __shared__ float lds_s[4][64];
  __shared__ float lds_q[4][64];
  const int t = threadIdx.x;
  const int lane = t & 63;
  const int slice = t >> 6;               // 0..3
  const int c = blockIdx.x * 64 + lane;   // 0..3071
  float s = 0.f, q = 0.f;
  #pragma unroll 8
  for (int i = 0; i < 32; ++i) {
    int ch = slice * 32 + i;              // 0..127
    s += P.psum[(size_t)ch * NC + c];
    q += P.psq [(size_t)ch * NC + c];
  }
  lds_s[slice][lane] = s;
  lds_q[slice][lane] = q;
  // absorb the memset: zero the K3 atomic accumulators (1024 floats each)
  if (blockIdx.x == 0) ((float4*)P.osum)[t] = float4{0.f, 0.f, 0.f, 0.f};
  if (blockIdx.x == 1) ((float4*)P.osq )[t] = float4{0.f, 0.f, 0.f, 0.f};
  __syncthreads();
  if (t < 64) {
    float ss = lds_s[0][t] + lds_s[1][t] + lds_s[2][t] + lds_s[3][t];
    float qq = lds_q[0][t] + lds_q[1][t] + lds_q[2][t] + lds_q[3][t];
    float mean = ss / NROWS;
    float var = qq / NROWS - mean * mean;
    if (var < 0.f) var = 0.f;
    qr_coef(P, blockIdx.x * 64 + t, mean, var);
  }
}

// ============ K3: contraction + store o fp16 + atomic out-stats ============
// grid (4, 256), block 256 (4 waves). launch_bounds(256,3): VGPR cap ~170 --
// A/B vs r14's (256,2): targets 12 waves/CU (vs 8) if the ~100-130-reg live
// set fits without spill. r9 showed 64-reg cap spills; 170 should not.
__global__ __launch_bounds__(256, 3) void k3_main(Params P) {
  __shared__ float4 lds_s[4][64];
  __shared__ float4 lds_q[4][64];
  const int t = threadIdx.x;
  const int lane = t & 63;
  const int slice = t >> 6;
  const int tg = blockIdx.x * 64 + lane;  // float4 d-group 0..255
  const int r0 = blockIdx.y * 32 + slice * 8;
  const float4* x4 = (const float4*)P.x;
  ushort4* o4 = (ushort4*)P.o_arr;
  CoefReg C = load_coefs(P, tg);
  float4 s = {0,0,0,0}, q = {0,0,0,0};
  #pragma unroll
  for (int r = 0; r < 8; ++r) {
    size_t base = (size_t)(r0 + r) * NG;
    float4 xq = x4[base + tg];
    float4 xk = x4[base + 256 + tg];
    float4 xv = x4[base + 512 + tg];
    float4 ov = contract4(xq, xk, xv, C);
    ushort4 oh;
    oh.x = __half_as_ushort(__float2half(ov.x));
    oh.y = __half_as_ushort(__float2half(ov.y));
    oh.z = __half_as_ushort(__float2half(ov.z));
    oh.w = __half_as_ushort(__float2half(ov.w));
    o4[(size_t)(r0 + r) * DG + tg] = oh;
    acc4(s, q, ov);
  }
  lds_s[slice][lane] = s;
  lds_q[slice][lane] = q;
  __syncthreads();
  float ssum = 0.f, ssq = 0.f;
  #pragma unroll
  for (int i = 0; i < 4; ++i) {
    ssum += ((const float*)&lds_s[i][t >> 2])[t & 3];
    ssq  += ((const float*)&lds_q[i][t >> 2])[t & 3];
  }
  atomicAdd(&P.osum[blockIdx.x * 256 + t], ssum);
  atomicAdd(&P.osq[blockIdx.x * 256 + t], ssq);
}

// ============ K4: per-thread stats recompute + normalize + write ============
// grid 2048, block 256 (4 rows/block). m/sc derived from the 8 KB
// accumulators (L2-broadcast) -- no separate stats kernel.
__global__ __launch_bounds__(256, 8) void k4_final(Params P) {
  const int t = threadIdx.x;
  float4 s4 = ((const float4*)P.osum)[t];
  float4 q4 = ((const float4*)P.osq)[t];
  float4 g4 = ((const float4*)P.g_out)[t];
  float4 b4 = ((const float4*)P.b_out)[t];
  float4 m, sc;
  #pragma unroll
  for (int kk = 0; kk < 4; ++kk) {
    float mean = ((const float*)&s4)[kk] / NROWS;
    float var = ((const float*)&q4)[kk] / NROWS - mean * mean;
    if (var < 0.f) var = 0.f;
    ((float*)&m)[kk] = mean;
    ((float*)&sc)[kk] = ((const float*)&g4)[kk] / sqrtf(var + EPS_NORM);
  }
  const int r0 = blockIdx.x * 4;
  const ushort4* o4 = (const ushort4*)P.o_arr;
  float4* out4 = (float4*)P.out;
  #pragma unroll
  for (int rr = 0; rr < 4; ++rr) {
    size_t idx = (size_t)(r0 + rr) * DG + t;
    ushort4 oh = o4[idx];
    nfloat4 y;
    y.x = (__half2float(__ushort_as_half(oh.x)) - m.x) * sc.x + b4.x;
    y.y = (__half2float(__ushort_as_half(oh.y)) - m.y) * sc.y + b4.y;
    y.z = (__half2float(__ushort_as_half(oh.z)) - m.z) * sc.z + b4.z;
    y.w = (__half2float(__ushort_as_half(oh.w)) - m.w) * sc.w + b4.w;
    __builtin_nontemporal_store(y, (nfloat4*)&out4[idx]);
  }
}

}  // namespace

extern "C" void kernel_launch(void* const* d_in, const int* in_sizes, int n_in,
                              void* d_out, int out_size, void* d_ws, size_t ws_size,
                              hipStream_t stream) {
  Params P;
  P.x     = (const float*)d_in[0];
  P.wq    = (const float*)d_in[1];
  P.aq    = (const float*)d_in[3];
  P.gq    = (const float*)d_in[4];
  P.betaq = (const float*)d_in[5];
  P.wk    = (const float*)d_in[6];
  P.ak    = (const float*)d_in[8];
  P.gk    = (const float*)d_in[9];
  P.betak = (const float*)d_in[10];
  P.wv    = (const float*)d_in[11];
  P.av    = (const float*)d_in[13];
  P.gv    = (const float*)d_in[14];
  P.betav = (const float*)d_in[15];
  P.g_out = (const float*)d_in[16];
  P.b_out = (const float*)d_in[17];
  P.out   = (float*)d_out;

  float* ws = (float*)d_ws;
  P.psum  = ws;  ws += (size_t)CH1 * NC;   // 1.57 MB
  P.psq   = ws;  ws += (size_t)CH1 * NC;   // 1.57 MB
  P.osum  = ws;  ws += DD;
  P.osq   = ws;  ws += DD;
  P.A_arr = ws;  ws += 3 * NC;
  P.B_arr = ws;  ws += 3 * NC;
  P.o_arr = (unsigned short*)ws;           // 16 MB fp16 [NROWS][DD]

  k1_col_stats<<<dim3(12, CH1), dim3(256), 0, stream>>>(P);
  k2_coef<<<dim3(48), dim3(256), 0, stream>>>(P);
  k3_main<<<dim3(4, 256), dim3(256), 0, stream>>>(P);
  k4_final<<<dim3(2048), dim3(256), 0, stream>>>(P);
}